// Round 7
// baseline (754.314 us; speedup 1.0000x reference)
//
#include <hip/hip_runtime.h>
#include <hip/hip_bf16.h>

typedef __attribute__((ext_vector_type(4))) float f4;
typedef __attribute__((ext_vector_type(8))) _Float16 h8;
typedef __attribute__((ext_vector_type(4))) _Float16 h4;
typedef __attribute__((ext_vector_type(2))) __fp16 hp2;   // native type of cvt_pkrtz

#define MTOT 131072   // LP*B == B*LQ rows per big GEMM

__device__ __forceinline__ float fast_tanh(float x){
    float e = exp2f(x * 2.8853900817779268f);
    return 1.0f - 2.0f * __builtin_amdgcn_rcpf(e + 1.0f);
}
__device__ __forceinline__ float fast_sigmoid(float x){
    return __builtin_amdgcn_rcpf(1.0f + exp2f(-x * 1.4426950408889634f));
}
__device__ __forceinline__ float wave_reduce_sum(float v){
    #pragma unroll
    for (int off = 32; off; off >>= 1) v += __shfl_down(v, off, 64);
    return v;
}

// ---------- pack both W (fp32 [512][512]) into fp16 MFMA-fragment order ----------
// chunk idx = n16*16 + kt: 1 KB where lane l holds W[n16*16+(l&15)][kt*32+(l>>4)*8 ..+8]
__global__ __launch_bounds__(256) void k_pack_both(
    const float* __restrict__ Wu, const float* __restrict__ Wh,
    _Float16* __restrict__ Pu, _Float16* __restrict__ Ph)
{
    const int g = blockIdx.x;                 // 0..255
    const float* W = (g < 128) ? Wu : Wh;
    _Float16*    P = (g < 128) ? Pu : Ph;
    const int idx = (g & 127) * 4 + (threadIdx.x >> 6);   // 0..511
    const int l = threadIdx.x & 63;
    const int n = (idx >> 4) * 16 + (l & 15);
    const int k = (idx & 15) * 32 + (l >> 4) * 8;
    const float* src = W + n * 512 + k;
    f4 s0 = *(const f4*)(src);
    f4 s1 = *(const f4*)(src + 4);
    h8 v;
    #pragma unroll
    for (int i = 0; i < 4; i++){ v[i] = (_Float16)s0[i]; v[4+i] = (_Float16)s1[i]; }
    *(h8*)(P + (idx << 9) + l * 8) = v;
}

// ---------- big fused GEMM:  s[row] = vb[b] . tanh(A_row @ W^T + add) ----------
// A reg-staged with pack-to-fp16 (convert ONCE per element), fp16 LDS (8 KB/buf,
// XOR-swizzled, conflict-free); W read directly from L2-resident fragment-packed
// buffer (no W LDS); raw s_barrier + lgkmcnt(0) only (no vmcnt drain) so the
// depth-2 A register prefetch stays in flight across barriers.
union SMemG {
    _Float16 A[2][128][32];   // 16384 B
    _Float16 ep[64][264];     // 33792 B epilogue tile
};
union HU { h8 v; hp2 p[4]; };

template<int MODE>
__global__ __launch_bounds__(512, 4) void k_score_gemm(
    const float* __restrict__ A,
    const _Float16* __restrict__ Wp,
    const float* __restrict__ vb,
    const float* __restrict__ addvec,
    float* __restrict__ spart,
    _Float16* __restrict__ whh)
{
    __shared__ __align__(16) SMemG sm;

    const int tid  = threadIdx.x;
    const int lane = tid & 63;
    const int wv   = tid >> 6;      // 0..7
    const int wr   = wv >> 2;       // 0..1
    const int wc   = wv & 3;        // 0..3
    const int mt   = blockIdx.x >> 1;
    const int nc   = blockIdx.x & 1;
    const int m0   = mt * 128;
    const int n0   = nc * 256;

    const int lr = lane & 15;
    const int kq = lane >> 4;

    // staging: thread t covers A[row=t>>2][ (t&3)*8 .. +8 ) of each 32-k chunk
    const int srow = tid >> 2;
    const int sg   = tid & 3;
    const int sgp  = sg ^ ((srow >> 1) & 3);           // swizzled 16B granule
    const float* agbase = A + (long)(m0 + srow) * 512 + sg * 8;
    _Float16* swr = &sm.A[0][0][0] + srow * 32 + sgp * 8;

    const _Float16* wbase = Wp + (nc * 16 + wc * 4) * 16 * 512 + lane * 8;

    f4 apf[3][2];
    auto issueA = [&](int kt){
        const float* p = agbase + kt * 32;
        apf[kt % 3][0] = *(const f4*)p;
        apf[kt % 3][1] = *(const f4*)(p + 4);
    };
    auto writeA = [&](int kt){
        HU u;
        u.p[0] = __builtin_amdgcn_cvt_pkrtz(apf[kt % 3][0][0], apf[kt % 3][0][1]);
        u.p[1] = __builtin_amdgcn_cvt_pkrtz(apf[kt % 3][0][2], apf[kt % 3][0][3]);
        u.p[2] = __builtin_amdgcn_cvt_pkrtz(apf[kt % 3][1][0], apf[kt % 3][1][1]);
        u.p[3] = __builtin_amdgcn_cvt_pkrtz(apf[kt % 3][1][2], apf[kt % 3][1][3]);
        *(h8*)(swr + (kt & 1) * 4096) = u.v;
    };

    issueA(0); issueA(1); issueA(2);
    writeA(0);
    __syncthreads();

    f4 acc[4][4] = {};

    #pragma unroll
    for (int kt = 0; kt < 16; ++kt){
        const int cur = kt & 1;
        h8 af[4];
        #pragma unroll
        for (int mi = 0; mi < 4; mi++){
            const int row = wr*64 + mi*16 + lr;
            const int gp  = kq ^ ((row >> 1) & 3);
            af[mi] = *(const h8*)(&sm.A[cur][0][0] + row * 32 + gp * 8);
        }
        h8 bf[4];
        #pragma unroll
        for (int ni = 0; ni < 4; ni++)
            bf[ni] = *(const h8*)(wbase + (ni * 16 + kt) * 512);

        if (kt < 15)     writeA(kt + 1);     // pack+store next chunk (regs already in flight)
        if (kt + 3 < 16) issueA(kt + 3);     // refill freed slot: 2 iterations of slack

        __builtin_amdgcn_s_setprio(1);
        #pragma unroll
        for (int mi = 0; mi < 4; mi++)
            #pragma unroll
            for (int ni = 0; ni < 4; ni++)
                acc[mi][ni] = __builtin_amdgcn_mfma_f32_16x16x32_f16(af[mi], bf[ni], acc[mi][ni], 0, 0, 0);
        __builtin_amdgcn_s_setprio(0);

        // barrier WITHOUT vmcnt drain: ds ops complete, global prefetch stays in flight
        asm volatile("s_waitcnt lgkmcnt(0)" ::: "memory");
        __builtin_amdgcn_sched_barrier(0);
        __builtin_amdgcn_s_barrier();
        __builtin_amdgcn_sched_barrier(0);
    }
    __syncthreads();

    // ---- epilogue (verified rounds 1-5): LDS tile reuse ----
    const int jrow = (lane >> 4) * 4;
    for (int hf = 0; hf < 2; ++hf){
        if (wr == hf){
            #pragma unroll
            for (int mi = 0; mi < 4; mi++)
                #pragma unroll
                for (int ni = 0; ni < 4; ni++)
                    #pragma unroll
                    for (int j = 0; j < 4; j++)
                        sm.ep[mi*16 + jrow + j][wc*64 + ni*16 + lr] = (_Float16)acc[mi][ni][j];
        }
        __syncthreads();

        if (MODE == 1 && whh){
            const int row = tid >> 3, seg = tid & 7;
            const int m = m0 + hf*64 + row;
            const _Float16* esrc = &sm.ep[row][seg*32];
            _Float16* gdst = whh + (long)m*512 + n0 + seg*32;
            #pragma unroll
            for (int i = 0; i < 4; i++)
                *(h8*)(gdst + i*8) = *(const h8*)(esrc + i*8);
        }

        #pragma unroll
        for (int rr = 0; rr < 8; ++rr){
            const int erow = wv*8 + rr;
            const int m = m0 + hf*64 + erow;
            const int b = (MODE == 0) ? (m >> 12) : (m & 31);
            const int n = n0 + lane*4;
            h4 hv = *(const h4*)&sm.ep[erow][lane*4];
            f4 vbv = *(const f4*)&vb[b*512 + n];
            f4 adv;
            if (MODE == 0) adv = *(const f4*)&addvec[n];
            else           adv = *(const f4*)&addvec[b*512 + n];
            float p = 0.f;
            #pragma unroll
            for (int i = 0; i < 4; i++)
                p += fast_tanh((float)hv[i] + adv[i]) * vbv[i];
            p = wave_reduce_sum(p);
            if (lane == 0){
                const int sIdx = (MODE == 0) ? m : (((m & 31) << 12) | (m >> 5));
                spart[nc*MTOT + sIdx] = p;
            }
        }
        __syncthreads();
    }
}

// ---------- softmax over 4096, optionally summing two partial-score arrays ----------
__global__ __launch_bounds__(256) void k_softmax(const float* __restrict__ s0,
        const float* __restrict__ s1, float* __restrict__ out)
{
    __shared__ float red[8];
    __shared__ float bcast[2];
    const int b = blockIdx.x, t = threadIdx.x;
    const int wv = t >> 6, lane = t & 63;
    const float* p0 = s0 + b*4096;
    const float* p1 = s1 ? s1 + b*4096 : nullptr;
    float vals[16];
    float mx = -3.0e38f;
    #pragma unroll
    for (int i = 0; i < 16; i++){
        float v = p0[t + i*256];
        if (p1) v += p1[t + i*256];
        vals[i] = v;
        mx = fmaxf(mx, v);
    }
    #pragma unroll
    for (int off = 32; off; off >>= 1) mx = fmaxf(mx, __shfl_down(mx, off, 64));
    if (lane == 0) red[wv] = mx;
    __syncthreads();
    if (t == 0) bcast[0] = fmaxf(fmaxf(red[0], red[1]), fmaxf(red[2], red[3]));
    __syncthreads();
    const float gmax = bcast[0];
    float sum = 0.f;
    #pragma unroll
    for (int i = 0; i < 16; i++){
        vals[i] = exp2f((vals[i] - gmax) * 1.4426950408889634f);
        sum += vals[i];
    }
    sum = wave_reduce_sum(sum);
    if (lane == 0) red[wv] = sum;
    __syncthreads();
    if (t == 0) bcast[1] = red[0] + red[1] + red[2] + red[3];
    __syncthreads();
    const float inv = 1.0f / bcast[1];
    #pragma unroll
    for (int i = 0; i < 16; i++) out[b*4096 + t + i*256] = vals[i] * inv;
}

// ---------- weighted row-sum: part[ch][b][d] = sum_q wts[b][q] * X[row(q,b)][d] ----------
__global__ __launch_bounds__(512) void k_weighted_rowsum(
    const float* __restrict__ wts, const float* __restrict__ X,
    float* __restrict__ part, int mode)
{
    const int b = blockIdx.x, ch = blockIdx.y, d = threadIdx.x;
    float acc = 0.f;
    const int q0 = ch * 128;
    for (int q = q0; q < q0 + 128; ++q){
        const float w = wts[b*4096 + q];
        if (fabsf(w) > 1e-20f){   // block-uniform branch; softmax weights mostly 0
            const float* xp = (mode == 0) ? (X + ((long)(b*4096 + q) * 512) + d)
                                          : (X + ((long)(q*32 + b) * 512) + d);
            acc += w * xp[0];
        }
    }
    part[(ch*32 + b)*512 + d] = acc;
}

__global__ void k_reduce_part(const float* __restrict__ part, float* __restrict__ out){
    const int b = blockIdx.x, d = threadIdx.x;
    float s = 0.f;
    #pragma unroll
    for (int ch = 0; ch < 32; ++ch) s += part[(ch*32 + b)*512 + d];
    out[b*512 + d] = s;
}

// ---------- small matvec: out[b][row] = W[row,:] . x[b,:] (+bias), K=512 ----------
__global__ __launch_bounds__(256) void k_matvec(
    const float* __restrict__ W, const float* __restrict__ x,
    const float* __restrict__ bias, float* __restrict__ out, int N)
{
    __shared__ float xs[512];
    const int b = blockIdx.x, t = threadIdx.x;
    xs[t] = x[b*512 + t];
    xs[t + 256] = x[b*512 + 256 + t];
    __syncthreads();
    const int wv = t >> 6, lane = t & 63;
    f4 x0 = *(const f4*)&xs[lane*8];
    f4 x1 = *(const f4*)&xs[lane*8 + 4];
    const int rbase = blockIdx.y*32 + wv*8;
    for (int rr = 0; rr < 8; ++rr){
        const int row = rbase + rr;
        const float* wp = W + (long)row*512 + lane*8;
        f4 w0 = *(const f4*)wp;
        f4 w1 = *(const f4*)(wp + 4);
        float p = w0[0]*x0[0] + w0[1]*x0[1] + w0[2]*x0[2] + w0[3]*x0[3]
                + w1[0]*x1[0] + w1[1]*x1[1] + w1[2]*x1[2] + w1[3]*x1[3];
        p = wave_reduce_sum(p);
        if (lane == 0) out[b*N + row] = p + (bias ? bias[row] : 0.f);
    }
}

// ---------- GRU gates ----------
__global__ void k_gru(const float* __restrict__ gi, const float* __restrict__ gh,
                      const float* __restrict__ r, float* __restrict__ r2)
{
    const int b = blockIdx.x, d = threadIdx.x;
    const float* gib = gi + b*1536;
    const float* ghb = gh + b*1536;
    const float rg = fast_sigmoid(gib[d]        + ghb[d]);
    const float z  = fast_sigmoid(gib[512 + d]  + ghb[512 + d]);
    const float n  = fast_tanh   (gib[1024 + d] + rg * ghb[1024 + d]);
    r2[b*512 + d] = (1.f - z)*n + z*r[b*512 + d];
}

// ---------- second h-attention scores from cached Whh16 ----------
__global__ __launch_bounds__(256) void k_t2(const _Float16* __restrict__ whh,
        const float* __restrict__ vb, const float* __restrict__ ra2, float* __restrict__ t2)
{
    const int wv = threadIdx.x >> 6, lane = threadIdx.x & 63;
    const int mbase = blockIdx.x*32 + wv*8;
    for (int rr = 0; rr < 8; ++rr){
        const int m = mbase + rr;
        const int b = m & 31;
        h8 hv = *(const h8*)(whh + (long)m*512 + lane*8);
        const float* rp  = ra2 + b*512 + lane*8;
        const float* vbp = vb  + b*512 + lane*8;
        float p = 0.f;
        #pragma unroll
        for (int i = 0; i < 8; i++)
            p += fast_tanh((float)hv[i] + rp[i]) * vbp[i];
        p = wave_reduce_sum(p);
        if (lane == 0) t2[((m & 31) << 12) | (m >> 5)] = p;
    }
}

extern "C" void kernel_launch(void* const* d_in, const int* in_sizes, int n_in,
                              void* d_out, int out_size, void* d_ws, size_t ws_size,
                              hipStream_t stream)
{
    const float* h_    = (const float*)d_in[0];
    const float* u_    = (const float*)d_in[1];
    const float* vb    = (const float*)d_in[2];   // (B,D,1) contiguous == (B,D)
    const float* Wu_w  = (const float*)d_in[3];
    const float* Wu_b  = (const float*)d_in[4];
    const float* Wh_w  = (const float*)d_in[5];
    const float* Wha_w = (const float*)d_in[6];
    const float* W_ih  = (const float*)d_in[7];
    const float* W_hh  = (const float*)d_in[8];
    const float* b_ih  = (const float*)d_in[9];
    const float* b_hh  = (const float*)d_in[10];
    float* out = (float*)d_out;

    char* ws = (char*)d_ws;
    float*    spart = (float*)(ws + 0);            // [2][131072]
    float*    tpart = (float*)(ws + 1048576);      // [2][131072]
    float*    a_    = (float*)(ws + 2097152);      // [32][4096]
    _Float16* Wpu   = (_Float16*)(ws + 2621440);   // 512x512 fp16, fragment-packed
    _Float16* Wph   = (_Float16*)(ws + 3145728);
    float*    r_    = (float*)(ws + 3670016);      // [32][512]
    float*    ra1   = (float*)(ws + 3735552);
    float*    c_    = (float*)(ws + 3801088);
    float*    r2    = (float*)(ws + 3866624);
    float*    ra2   = (float*)(ws + 3932160);
    float*    gi    = (float*)(ws + 3997696);      // [32][1536]
    float*    gh    = (float*)(ws + 4194304);
    float*    part  = (float*)(ws + 4390912);      // [32][32][512] = 2 MB, reused
    _Float16* whh   = (_Float16*)(ws + 8388608);   // [131072][512] fp16 = 128 MB
    const bool big = ws_size >= (size_t)8388608 + (size_t)MTOT * 512 * 2;

    k_pack_both<<<256, 256, 0, stream>>>(Wu_w, Wh_w, Wpu, Wph);

    // u-side attention -> a -> r -> ra1
    k_score_gemm<0><<<2048, 512, 0, stream>>>(u_, Wpu, vb, Wu_b, spart, nullptr);
    k_softmax<<<32, 256, 0, stream>>>(spart, spart + MTOT, a_);
    k_weighted_rowsum<<<dim3(32, 32), 512, 0, stream>>>(a_, u_, part, 0);
    k_reduce_part<<<32, 512, 0, stream>>>(part, r_);
    k_matvec<<<dim3(32, 16), 256, 0, stream>>>(Wha_w, r_, nullptr, ra1, 512);

    // h-side attention #1 (stores Whh_proj fp16) -> p1
    k_score_gemm<1><<<2048, 512, 0, stream>>>(h_, Wph, vb, ra1, tpart, big ? whh : nullptr);
    k_softmax<<<32, 256, 0, stream>>>(tpart, tpart + MTOT, out);          // p1

    // c = p1 . h ; GRU ; ra2
    k_weighted_rowsum<<<dim3(32, 32), 512, 0, stream>>>(out, h_, part, 1);
    k_reduce_part<<<32, 512, 0, stream>>>(part, c_);
    k_matvec<<<dim3(32, 48), 256, 0, stream>>>(W_ih, c_, b_ih, gi, 1536);
    k_matvec<<<dim3(32, 48), 256, 0, stream>>>(W_hh, r_, b_hh, gh, 1536);
    k_gru<<<32, 512, 0, stream>>>(gi, gh, r_, r2);
    k_matvec<<<dim3(32, 16), 256, 0, stream>>>(Wha_w, r2, nullptr, ra2, 512);

    // h-side attention #2 -> p2
    if (big){
        k_t2<<<4096, 256, 0, stream>>>(whh, vb, ra2, tpart);
        k_softmax<<<32, 256, 0, stream>>>(tpart, nullptr, out + MTOT);
    } else {
        k_score_gemm<2><<<2048, 512, 0, stream>>>(h_, Wph, vb, ra2, tpart, nullptr);
        k_softmax<<<32, 256, 0, stream>>>(tpart, tpart + MTOT, out + MTOT);
    }
}

// Round 8
// 584.459 us; speedup vs baseline: 1.2906x; 1.2906x over previous
//
#include <hip/hip_runtime.h>
#include <hip/hip_bf16.h>

typedef __attribute__((ext_vector_type(4))) float f4;
typedef __attribute__((ext_vector_type(8))) _Float16 h8;
typedef __attribute__((ext_vector_type(4))) _Float16 h4;
typedef __attribute__((ext_vector_type(2))) __fp16 hp2;   // native type of cvt_pkrtz

#define MTOT 131072   // LP*B == B*LQ rows per big GEMM

__device__ __forceinline__ float fast_tanh(float x){
    float e = exp2f(x * 2.8853900817779268f);
    return 1.0f - 2.0f * __builtin_amdgcn_rcpf(e + 1.0f);
}
__device__ __forceinline__ float fast_sigmoid(float x){
    return __builtin_amdgcn_rcpf(1.0f + exp2f(-x * 1.4426950408889634f));
}
__device__ __forceinline__ float wave_reduce_sum(float v){
    #pragma unroll
    for (int off = 32; off; off >>= 1) v += __shfl_down(v, off, 64);
    return v;
}

// ---------- pack both W (fp32 [512][512]) into fp16 MFMA-fragment order ----------
// chunk idx = n16*16 + kt: 1 KB where lane l holds W[n16*16+(l&15)][kt*32+(l>>4)*8 ..+8]
__global__ __launch_bounds__(256) void k_pack_both(
    const float* __restrict__ Wu, const float* __restrict__ Wh,
    _Float16* __restrict__ Pu, _Float16* __restrict__ Ph)
{
    const int g = blockIdx.x;                 // 0..255
    const float* W = (g < 128) ? Wu : Wh;
    _Float16*    P = (g < 128) ? Pu : Ph;
    const int idx = (g & 127) * 4 + (threadIdx.x >> 6);   // 0..511
    const int l = threadIdx.x & 63;
    const int n = (idx >> 4) * 16 + (l & 15);
    const int k = (idx & 15) * 32 + (l >> 4) * 8;
    const float* src = W + n * 512 + k;
    f4 s0 = *(const f4*)(src);
    f4 s1 = *(const f4*)(src + 4);
    h8 v;
    #pragma unroll
    for (int i = 0; i < 4; i++){ v[i] = (_Float16)s0[i]; v[4+i] = (_Float16)s1[i]; }
    *(h8*)(P + (idx << 9) + l * 8) = v;
}

// ---------- big fused GEMM:  s[row] = vb[b] . tanh(A_row @ W^T + add) ----------
// A reg-staged with pack-to-fp16 (convert ONCE per element), fp16 LDS (8 KB/buf,
// XOR-swizzled, conflict-free); W double-buffered in REGISTERS from L2-resident
// fragment-packed buffer (no W LDS); raw s_barrier + lgkmcnt(0) only (no vmcnt
// drain) so the depth-4 A prefetch + depth-2 W prefetch stay in flight across
// barriers. launch_bounds(512,2): 256-VGPR budget -> NO SPILLS (round-7 lesson:
// (512,4) = 128 budget spilled the prefetch ring, +490 MB HBM scratch traffic).
union SMemG {
    _Float16 A[2][128][32];   // 16384 B
    _Float16 ep[64][264];     // 33792 B epilogue tile
};
union HU { h8 v; hp2 p[4]; };

template<int MODE>
__global__ __launch_bounds__(512, 2) void k_score_gemm(
    const float* __restrict__ A,
    const _Float16* __restrict__ Wp,
    const float* __restrict__ vb,
    const float* __restrict__ addvec,
    float* __restrict__ spart,
    _Float16* __restrict__ whh)
{
    __shared__ __align__(16) SMemG sm;

    const int tid  = threadIdx.x;
    const int lane = tid & 63;
    const int wv   = tid >> 6;      // 0..7
    const int wr   = wv >> 2;       // 0..1
    const int wc   = wv & 3;        // 0..3
    const int mt   = blockIdx.x >> 1;
    const int nc   = blockIdx.x & 1;
    const int m0   = mt * 128;
    const int n0   = nc * 256;

    const int lr = lane & 15;
    const int kq = lane >> 4;

    // staging: thread t covers A[row=t>>2][ (t&3)*8 .. +8 ) of each 32-k chunk
    const int srow = tid >> 2;
    const int sg   = tid & 3;
    const int sgp  = sg ^ ((srow >> 1) & 3);           // swizzled 16B granule
    const float* agbase = A + (long)(m0 + srow) * 512 + sg * 8;
    _Float16* swr = &sm.A[0][0][0] + srow * 32 + sgp * 8;

    const _Float16* wbase = Wp + (nc * 16 + wc * 4) * 16 * 512 + lane * 8;

    f4 apf[4][2];            // depth-4 A ring: 3 iterations of HBM slack
    h8 bpf[2][4];            // W register double-buffer: 1 iteration of L2 slack

    auto issueA = [&](int kt){
        const float* p = agbase + kt * 32;
        apf[kt & 3][0] = *(const f4*)p;
        apf[kt & 3][1] = *(const f4*)(p + 4);
    };
    auto issueW = [&](int kt){
        #pragma unroll
        for (int ni = 0; ni < 4; ni++)
            bpf[kt & 1][ni] = *(const h8*)(wbase + (ni * 16 + kt) * 512);
    };
    auto writeA = [&](int kt){
        HU u;
        u.p[0] = __builtin_amdgcn_cvt_pkrtz(apf[kt & 3][0][0], apf[kt & 3][0][1]);
        u.p[1] = __builtin_amdgcn_cvt_pkrtz(apf[kt & 3][0][2], apf[kt & 3][0][3]);
        u.p[2] = __builtin_amdgcn_cvt_pkrtz(apf[kt & 3][1][0], apf[kt & 3][1][1]);
        u.p[3] = __builtin_amdgcn_cvt_pkrtz(apf[kt & 3][1][2], apf[kt & 3][1][3]);
        *(h8*)(swr + (kt & 1) * 4096) = u.v;
    };

    issueA(0); issueA(1); issueA(2); issueA(3);
    issueW(0);
    writeA(0);
    __syncthreads();

    f4 acc[4][4] = {};

    #pragma unroll
    for (int kt = 0; kt < 16; ++kt){
        const int cur = kt & 1;
        h8 af[4];
        #pragma unroll
        for (int mi = 0; mi < 4; mi++){
            const int row = wr*64 + mi*16 + lr;
            const int gp  = kq ^ ((row >> 1) & 3);
            af[mi] = *(const h8*)(&sm.A[cur][0][0] + row * 32 + gp * 8);
        }
        if (kt < 15){
            issueW(kt + 1);                  // W for next iteration (L2-hit)
            writeA(kt + 1);                  // pack+store next A chunk
        }
        if (kt + 4 < 16) issueA(kt + 4);     // refill freed ring slot: 3 iters slack

        __builtin_amdgcn_s_setprio(1);
        #pragma unroll
        for (int mi = 0; mi < 4; mi++)
            #pragma unroll
            for (int ni = 0; ni < 4; ni++)
                acc[mi][ni] = __builtin_amdgcn_mfma_f32_16x16x32_f16(af[mi], bpf[cur][ni], acc[mi][ni], 0, 0, 0);
        __builtin_amdgcn_s_setprio(0);

        // barrier WITHOUT vmcnt drain: ds ops complete, global prefetch stays in flight
        asm volatile("s_waitcnt lgkmcnt(0)" ::: "memory");
        __builtin_amdgcn_sched_barrier(0);
        __builtin_amdgcn_s_barrier();
        __builtin_amdgcn_sched_barrier(0);
    }
    __syncthreads();

    // ---- epilogue (verified rounds 1-7): LDS tile reuse ----
    const int jrow = (lane >> 4) * 4;
    for (int hf = 0; hf < 2; ++hf){
        if (wr == hf){
            #pragma unroll
            for (int mi = 0; mi < 4; mi++)
                #pragma unroll
                for (int ni = 0; ni < 4; ni++)
                    #pragma unroll
                    for (int j = 0; j < 4; j++)
                        sm.ep[mi*16 + jrow + j][wc*64 + ni*16 + lr] = (_Float16)acc[mi][ni][j];
        }
        __syncthreads();

        if (MODE == 1 && whh){
            const int row = tid >> 3, seg = tid & 7;
            const int m = m0 + hf*64 + row;
            const _Float16* esrc = &sm.ep[row][seg*32];
            _Float16* gdst = whh + (long)m*512 + n0 + seg*32;
            #pragma unroll
            for (int i = 0; i < 4; i++)
                *(h8*)(gdst + i*8) = *(const h8*)(esrc + i*8);
        }

        #pragma unroll
        for (int rr = 0; rr < 8; ++rr){
            const int erow = wv*8 + rr;
            const int m = m0 + hf*64 + erow;
            const int b = (MODE == 0) ? (m >> 12) : (m & 31);
            const int n = n0 + lane*4;
            h4 hv = *(const h4*)&sm.ep[erow][lane*4];
            f4 vbv = *(const f4*)&vb[b*512 + n];
            f4 adv;
            if (MODE == 0) adv = *(const f4*)&addvec[n];
            else           adv = *(const f4*)&addvec[b*512 + n];
            float p = 0.f;
            #pragma unroll
            for (int i = 0; i < 4; i++)
                p += fast_tanh((float)hv[i] + adv[i]) * vbv[i];
            p = wave_reduce_sum(p);
            if (lane == 0){
                const int sIdx = (MODE == 0) ? m : (((m & 31) << 12) | (m >> 5));
                spart[nc*MTOT + sIdx] = p;
            }
        }
        __syncthreads();
    }
}

// ---------- softmax over 4096, optionally summing two partial-score arrays ----------
__global__ __launch_bounds__(256) void k_softmax(const float* __restrict__ s0,
        const float* __restrict__ s1, float* __restrict__ out)
{
    __shared__ float red[8];
    __shared__ float bcast[2];
    const int b = blockIdx.x, t = threadIdx.x;
    const int wv = t >> 6, lane = t & 63;
    const float* p0 = s0 + b*4096;
    const float* p1 = s1 ? s1 + b*4096 : nullptr;
    float vals[16];
    float mx = -3.0e38f;
    #pragma unroll
    for (int i = 0; i < 16; i++){
        float v = p0[t + i*256];
        if (p1) v += p1[t + i*256];
        vals[i] = v;
        mx = fmaxf(mx, v);
    }
    #pragma unroll
    for (int off = 32; off; off >>= 1) mx = fmaxf(mx, __shfl_down(mx, off, 64));
    if (lane == 0) red[wv] = mx;
    __syncthreads();
    if (t == 0) bcast[0] = fmaxf(fmaxf(red[0], red[1]), fmaxf(red[2], red[3]));
    __syncthreads();
    const float gmax = bcast[0];
    float sum = 0.f;
    #pragma unroll
    for (int i = 0; i < 16; i++){
        vals[i] = exp2f((vals[i] - gmax) * 1.4426950408889634f);
        sum += vals[i];
    }
    sum = wave_reduce_sum(sum);
    if (lane == 0) red[wv] = sum;
    __syncthreads();
    if (t == 0) bcast[1] = red[0] + red[1] + red[2] + red[3];
    __syncthreads();
    const float inv = 1.0f / bcast[1];
    #pragma unroll
    for (int i = 0; i < 16; i++) out[b*4096 + t + i*256] = vals[i] * inv;
}

// ---------- weighted row-sum: part[ch][b][d] = sum_q wts[b][q] * X[row(q,b)][d] ----------
__global__ __launch_bounds__(512) void k_weighted_rowsum(
    const float* __restrict__ wts, const float* __restrict__ X,
    float* __restrict__ part, int mode)
{
    const int b = blockIdx.x, ch = blockIdx.y, d = threadIdx.x;
    float acc = 0.f;
    const int q0 = ch * 128;
    for (int q = q0; q < q0 + 128; ++q){
        const float w = wts[b*4096 + q];
        if (fabsf(w) > 1e-20f){   // block-uniform branch; softmax weights mostly 0
            const float* xp = (mode == 0) ? (X + ((long)(b*4096 + q) * 512) + d)
                                          : (X + ((long)(q*32 + b) * 512) + d);
            acc += w * xp[0];
        }
    }
    part[(ch*32 + b)*512 + d] = acc;
}

__global__ void k_reduce_part(const float* __restrict__ part, float* __restrict__ out){
    const int b = blockIdx.x, d = threadIdx.x;
    float s = 0.f;
    #pragma unroll
    for (int ch = 0; ch < 32; ++ch) s += part[(ch*32 + b)*512 + d];
    out[b*512 + d] = s;
}

// ---------- small matvec: out[b][row] = W[row,:] . x[b,:] (+bias), K=512 ----------
__global__ __launch_bounds__(256) void k_matvec(
    const float* __restrict__ W, const float* __restrict__ x,
    const float* __restrict__ bias, float* __restrict__ out, int N)
{
    __shared__ float xs[512];
    const int b = blockIdx.x, t = threadIdx.x;
    xs[t] = x[b*512 + t];
    xs[t + 256] = x[b*512 + 256 + t];
    __syncthreads();
    const int wv = t >> 6, lane = t & 63;
    f4 x0 = *(const f4*)&xs[lane*8];
    f4 x1 = *(const f4*)&xs[lane*8 + 4];
    const int rbase = blockIdx.y*32 + wv*8;
    for (int rr = 0; rr < 8; ++rr){
        const int row = rbase + rr;
        const float* wp = W + (long)row*512 + lane*8;
        f4 w0 = *(const f4*)wp;
        f4 w1 = *(const f4*)(wp + 4);
        float p = w0[0]*x0[0] + w0[1]*x0[1] + w0[2]*x0[2] + w0[3]*x0[3]
                + w1[0]*x1[0] + w1[1]*x1[1] + w1[2]*x1[2] + w1[3]*x1[3];
        p = wave_reduce_sum(p);
        if (lane == 0) out[b*N + row] = p + (bias ? bias[row] : 0.f);
    }
}

// ---------- GRU gates ----------
__global__ void k_gru(const float* __restrict__ gi, const float* __restrict__ gh,
                      const float* __restrict__ r, float* __restrict__ r2)
{
    const int b = blockIdx.x, d = threadIdx.x;
    const float* gib = gi + b*1536;
    const float* ghb = gh + b*1536;
    const float rg = fast_sigmoid(gib[d]        + ghb[d]);
    const float z  = fast_sigmoid(gib[512 + d]  + ghb[512 + d]);
    const float n  = fast_tanh   (gib[1024 + d] + rg * ghb[1024 + d]);
    r2[b*512 + d] = (1.f - z)*n + z*r[b*512 + d];
}

// ---------- second h-attention scores from cached Whh16 ----------
__global__ __launch_bounds__(256) void k_t2(const _Float16* __restrict__ whh,
        const float* __restrict__ vb, const float* __restrict__ ra2, float* __restrict__ t2)
{
    const int wv = threadIdx.x >> 6, lane = threadIdx.x & 63;
    const int mbase = blockIdx.x*32 + wv*8;
    for (int rr = 0; rr < 8; ++rr){
        const int m = mbase + rr;
        const int b = m & 31;
        h8 hv = *(const h8*)(whh + (long)m*512 + lane*8);
        const float* rp  = ra2 + b*512 + lane*8;
        const float* vbp = vb  + b*512 + lane*8;
        float p = 0.f;
        #pragma unroll
        for (int i = 0; i < 8; i++)
            p += fast_tanh((float)hv[i] + rp[i]) * vbp[i];
        p = wave_reduce_sum(p);
        if (lane == 0) t2[((m & 31) << 12) | (m >> 5)] = p;
    }
}

extern "C" void kernel_launch(void* const* d_in, const int* in_sizes, int n_in,
                              void* d_out, int out_size, void* d_ws, size_t ws_size,
                              hipStream_t stream)
{
    const float* h_    = (const float*)d_in[0];
    const float* u_    = (const float*)d_in[1];
    const float* vb    = (const float*)d_in[2];   // (B,D,1) contiguous == (B,D)
    const float* Wu_w  = (const float*)d_in[3];
    const float* Wu_b  = (const float*)d_in[4];
    const float* Wh_w  = (const float*)d_in[5];
    const float* Wha_w = (const float*)d_in[6];
    const float* W_ih  = (const float*)d_in[7];
    const float* W_hh  = (const float*)d_in[8];
    const float* b_ih  = (const float*)d_in[9];
    const float* b_hh  = (const float*)d_in[10];
    float* out = (float*)d_out;

    char* ws = (char*)d_ws;
    float*    spart = (float*)(ws + 0);            // [2][131072]
    float*    tpart = (float*)(ws + 1048576);      // [2][131072]
    float*    a_    = (float*)(ws + 2097152);      // [32][4096]
    _Float16* Wpu   = (_Float16*)(ws + 2621440);   // 512x512 fp16, fragment-packed
    _Float16* Wph   = (_Float16*)(ws + 3145728);
    float*    r_    = (float*)(ws + 3670016);      // [32][512]
    float*    ra1   = (float*)(ws + 3735552);
    float*    c_    = (float*)(ws + 3801088);
    float*    r2    = (float*)(ws + 3866624);
    float*    ra2   = (float*)(ws + 3932160);
    float*    gi    = (float*)(ws + 3997696);      // [32][1536]
    float*    gh    = (float*)(ws + 4194304);
    float*    part  = (float*)(ws + 4390912);      // [32][32][512] = 2 MB, reused
    _Float16* whh   = (_Float16*)(ws + 8388608);   // [131072][512] fp16 = 128 MB
    const bool big = ws_size >= (size_t)8388608 + (size_t)MTOT * 512 * 2;

    k_pack_both<<<256, 256, 0, stream>>>(Wu_w, Wh_w, Wpu, Wph);

    // u-side attention -> a -> r -> ra1
    k_score_gemm<0><<<2048, 512, 0, stream>>>(u_, Wpu, vb, Wu_b, spart, nullptr);
    k_softmax<<<32, 256, 0, stream>>>(spart, spart + MTOT, a_);
    k_weighted_rowsum<<<dim3(32, 32), 512, 0, stream>>>(a_, u_, part, 0);
    k_reduce_part<<<32, 512, 0, stream>>>(part, r_);
    k_matvec<<<dim3(32, 16), 256, 0, stream>>>(Wha_w, r_, nullptr, ra1, 512);

    // h-side attention #1 (stores Whh_proj fp16) -> p1
    k_score_gemm<1><<<2048, 512, 0, stream>>>(h_, Wph, vb, ra1, tpart, big ? whh : nullptr);
    k_softmax<<<32, 256, 0, stream>>>(tpart, tpart + MTOT, out);          // p1

    // c = p1 . h ; GRU ; ra2
    k_weighted_rowsum<<<dim3(32, 32), 512, 0, stream>>>(out, h_, part, 1);
    k_reduce_part<<<32, 512, 0, stream>>>(part, c_);
    k_matvec<<<dim3(32, 48), 256, 0, stream>>>(W_ih, c_, b_ih, gi, 1536);
    k_matvec<<<dim3(32, 48), 256, 0, stream>>>(W_hh, r_, b_hh, gh, 1536);
    k_gru<<<32, 512, 0, stream>>>(gi, gh, r_, r2);
    k_matvec<<<dim3(32, 16), 256, 0, stream>>>(Wha_w, r2, nullptr, ra2, 512);

    // h-side attention #2 -> p2
    if (big){
        k_t2<<<4096, 256, 0, stream>>>(whh, vb, ra2, tpart);
        k_softmax<<<32, 256, 0, stream>>>(tpart, nullptr, out + MTOT);
    } else {
        k_score_gemm<2><<<2048, 512, 0, stream>>>(h_, Wph, vb, ra2, tpart, nullptr);
        k_softmax<<<32, 256, 0, stream>>>(tpart, tpart + MTOT, out + MTOT);
    }
}